// Round 1
// baseline (13.382 us; speedup 1.0000x reference)
//
#include <hip/hip_runtime.h>
#include <math.h>

#define NN 128     // grid sidelength
#define NB 16384   // number of query points

// Faithful to reference: strict inequalities; |s|==1 or |s|>=2 -> 0.
__device__ __forceinline__ float cubic_conv(float s) {
    float a  = fabsf(s);
    float a2 = a * a;
    float a3 = a2 * a;
    float f1 =  1.5f * a3 - 2.5f * a2 + 1.0f;
    float f2 = -0.5f * a3 + 2.5f * a2 - 4.0f * a + 2.0f;
    return (a < 1.0f) ? f1 : ((a > 1.0f && a < 2.0f) ? f2 : 0.0f);
}

__global__ __launch_bounds__(64) void spline_fwd(
    const float* __restrict__ x,   // [B,2]
    const float* __restrict__ w,   // [N*N,1]
    const float* __restrict__ cp,  // [N*N,2], p = iy*N+ix -> (lin[ix], lin[iy])
    float* __restrict__ out)       // [B] output then [B,2] x passthrough
{
    int q = blockIdx.x * blockDim.x + threadIdx.x;
    if (q >= NB) return;

    float x0 = x[2 * q + 0];
    float x1 = x[2 * q + 1];
    // tuple output: (output[B], x[B,2]) concatenated flat
    out[NB + 2 * q + 0] = x0;
    out[NB + 2 * q + 1] = x1;

    const float h = 2.0f / 127.0f;   // == f32(2.0/(N-1)), same rounding as ref
    int cx = (int)floorf((x0 + 1.0f) / h);
    int cy = (int)floorf((x1 + 1.0f) / h);
    cx = min(max(cx, 0), NN - 1);
    cy = min(max(cy, 0), NN - 1);

    // Reference d2 expansion pieces
    float xx = x0 * x0 + x1 * x1;

    // 6x6 candidate window [cell-2, cell+3]; coords read from cp to match ref FP.
    float lx[6], ly[6];
    bool okx[6], oky[6];
    #pragma unroll
    for (int a = 0; a < 6; ++a) {
        int ix = cx - 2 + a;
        okx[a] = (ix >= 0) && (ix < NN);
        int ixc = min(max(ix, 0), NN - 1);
        lx[a] = cp[2 * ixc + 0];          // lin[ix] from row iy=0
        int iy = cy - 2 + a;
        oky[a] = (iy >= 0) && (iy < NN);
        int iyc = min(max(iy, 0), NN - 1);
        ly[a] = cp[2 * (iyc * NN) + 1];   // lin[iy] from col ix=0
    }

    // d2 for all 36 candidates, row-major (dy outer) == linear-index order.
    float d2[36];
    #pragma unroll
    for (int a = 0; a < 6; ++a) {
        #pragma unroll
        for (int b = 0; b < 6; ++b) {
            int k = a * 6 + b;
            if (oky[a] && okx[b]) {
                float dot = x0 * lx[b] + x1 * ly[a];
                float cc  = lx[b] * lx[b] + ly[a] * ly[a];
                d2[k] = xx - 2.0f * dot + cc;   // ref order: (xx - 2dot) + cc
            } else {
                d2[k] = INFINITY;               // nonexistent point
            }
        }
    }

    // Only the 4x4 support block (rows/cols 1..4 of the window) can contribute.
    // Include a support point iff its stable rank (top_k tie-break: lower index
    // first) among all candidates is < 16. Window rank == global rank since
    // all non-window points have d2 > 9h^2 > any support d2 (<= 8h^2).
    float result = 0.0f;
    #pragma unroll
    for (int a = 1; a <= 4; ++a) {
        #pragma unroll
        for (int b = 1; b <= 4; ++b) {
            if (!(oky[a] && okx[b])) continue;
            int k = a * 6 + b;
            float di = d2[k];
            int rank = 0;
            #pragma unroll
            for (int j = 0; j < 36; ++j) {
                bool less = (d2[j] < di) || ((d2[j] == di) && (j < k));
                rank += less ? 1 : 0;
            }
            if (rank < 16) {
                float sx = (x0 - lx[b]) / h;
                float sy = (x1 - ly[a]) / h;
                int p = (cy - 2 + a) * NN + (cx - 2 + b);
                result += w[p] * cubic_conv(sx) * cubic_conv(sy);
            }
        }
    }
    out[q] = result;
}

extern "C" void kernel_launch(void* const* d_in, const int* in_sizes, int n_in,
                              void* d_out, int out_size, void* d_ws, size_t ws_size,
                              hipStream_t stream) {
    const float* x  = (const float*)d_in[0];
    const float* w  = (const float*)d_in[1];
    const float* cp = (const float*)d_in[2];
    float* out = (float*)d_out;
    // 16384 queries, 64-thread blocks -> 256 blocks (1 per CU)
    spline_fwd<<<dim3(NB / 64), dim3(64), 0, stream>>>(x, w, cp, out);
}

// Round 2
// 9.680 us; speedup vs baseline: 1.3824x; 1.3824x over previous
//
#include <hip/hip_runtime.h>
#include <math.h>

#define NN 128     // grid sidelength
#define NB 16384   // number of query points

// Faithful to reference: strict inequalities; |s|==1 or |s|>=2 -> 0.
__device__ __forceinline__ float cubic_conv(float s) {
    float a  = fabsf(s);
    float a2 = a * a;
    float f1 = fmaf(a2, fmaf(1.5f, a, -2.5f), 1.0f);                    // 1.5a^3-2.5a^2+1
    float f2 = fmaf(fmaf(fmaf(-0.5f, a, 2.5f), a, -4.0f), a, 2.0f);     // -0.5a^3+2.5a^2-4a+2
    return (a < 1.0f) ? f1 : ((a > 1.0f && a < 2.0f) ? f2 : 0.0f);
}

// ---- compile-time dominance bounds -------------------------------------
// For frac f in [0,1], integer offsets a (of j) and b (of k):
// g(f) = (f-a)^2 - (f-b)^2 is linear; endpoints give exact integer bounds.
__host__ __device__ constexpr int axis_e0(int a, int b) { return a * a - b * b; }
__host__ __device__ constexpr int axis_e1(int a, int b) { return a * a - b * b - 2 * (a - b); }
__host__ __device__ constexpr int axis_lo(int a, int b) {
    return axis_e0(a, b) < axis_e1(a, b) ? axis_e0(a, b) : axis_e1(a, b);
}
__host__ __device__ constexpr int axis_hi(int a, int b) {
    return axis_e0(a, b) > axis_e1(a, b) ? axis_e0(a, b) : axis_e1(a, b);
}
// bounds of d2[j]-d2[k] (grid^2 units) over frac in [0,1]^2; window idx -> offset = idx-2
__host__ __device__ constexpr int pair_lo(int jr, int jc, int kr, int kc) {
    return axis_lo(jc - 2, kc - 2) + axis_lo(jr - 2, kr - 2);
}
__host__ __device__ constexpr int pair_hi(int jr, int jc, int kr, int kc) {
    return axis_hi(jc - 2, kc - 2) + axis_hi(jr - 2, kr - 2);
}
// hi < 0  => j ALWAYS strictly closer than k (margin >= h^2 >> FP noise)
// lo > 0  => j NEVER closer (strictly farther)
// else    => dynamic compare

__global__ __launch_bounds__(64) void spline_fwd(
    const float* __restrict__ x,   // [B,2]
    const float* __restrict__ w,   // [N*N,1]
    float* __restrict__ out)       // [B] output then [B,2] x passthrough
{
    int q = blockIdx.x * 64 + threadIdx.x;

    float x0 = x[2 * q + 0];
    float x1 = x[2 * q + 1];
    out[NB + 2 * q + 0] = x0;      // tuple output: (output[B], x[B,2])
    out[NB + 2 * q + 1] = x1;

    const float h = 2.0f / 127.0f;
    float vx = (x0 + 1.0f) / h;
    float vy = (x1 + 1.0f) / h;
    int cx = (int)floorf(vx);
    int cy = (int)floorf(vy);
    cx = min(max(cx, 0), NN - 1);
    cy = min(max(cy, 0), NN - 1);
    float fx = vx - (float)cx;     // frac in [0,1)
    float fy = vy - (float)cy;

    // ---- prefetch weights for the 4x4 support block (clamped; masked later) ----
    // Issued early so L2 gather latency hides under the rank computation.
    float wv[16];
    #pragma unroll
    for (int s = 0; s < 16; ++s) {
        int iy = min(max(cy - 1 + (s >> 2), 0), NN - 1);
        int ix = min(max(cx - 1 + (s & 3), 0), NN - 1);
        wv[s] = w[iy * NN + ix];
    }

    // ---- existence masks for the 6x6 window ----
    int exx[6], exy[6];
    #pragma unroll
    for (int a = 0; a < 6; ++a) {
        exx[a] = ((unsigned)(cx - 2 + a) < (unsigned)NN) ? 1 : 0;
        exy[a] = ((unsigned)(cy - 2 + a) < (unsigned)NN) ? 1 : 0;
    }

    // ---- d2 in grid^2 units; missing axis -> huge sentinel ----
    float sxv[6], syv[6], ux[6], uy[6];
    #pragma unroll
    for (int a = 0; a < 6; ++a) {
        sxv[a] = fx - (float)(a - 2);
        syv[a] = fy - (float)(a - 2);
        ux[a] = exx[a] ? sxv[a] * sxv[a] : 1.0e30f;
        uy[a] = exy[a] ? syv[a] * syv[a] : 1.0e30f;
    }
    float d2[36];
    #pragma unroll
    for (int a = 0; a < 6; ++a) {
        #pragma unroll
        for (int b = 0; b < 6; ++b) {
            d2[a * 6 + b] = uy[a] + ux[b];   // BIG if either axis missing
        }
    }

    // ---- ranks of the 16 support points among all 36 candidates ----
    int rank[16];
    #pragma unroll
    for (int s = 0; s < 16; ++s) rank[s] = 0;

    // (1) non-support j vs each support k (one-directional)
    #pragma unroll
    for (int ja = 0; ja < 6; ++ja) {
        #pragma unroll
        for (int jb = 0; jb < 6; ++jb) {
            if (ja >= 1 && ja <= 4 && jb >= 1 && jb <= 4) continue;  // support handled below
            #pragma unroll
            for (int ka = 1; ka <= 4; ++ka) {
                #pragma unroll
                for (int kb = 1; kb <= 4; ++kb) {
                    const int hi = pair_hi(ja, jb, ka, kb);
                    const int lo = pair_lo(ja, jb, ka, kb);
                    const int kidx = (ka - 1) * 4 + (kb - 1);
                    if (hi < 0) {
                        rank[kidx] += (exy[ja] & exx[jb]);           // always closer (if exists)
                    } else if (lo <= 0) {                            // dynamic
                        const int jlin = ja * 6 + jb, klin = ka * 6 + kb;
                        // top_k tie-break: lower linear index wins
                        bool t = (jlin < klin) ? (d2[jlin] <= d2[klin])
                                               : (d2[jlin] <  d2[klin]);
                        rank[kidx] += t ? 1 : 0;
                    } // lo > 0: never closer, no-op
                }
            }
        }
    }

    // (2) support-support pairs, each unordered pair handled once
    #pragma unroll
    for (int qa = 1; qa <= 4; ++qa) {
        #pragma unroll
        for (int qb = 1; qb <= 4; ++qb) {
            #pragma unroll
            for (int pa = 1; pa <= 4; ++pa) {
                #pragma unroll
                for (int pb = 1; pb <= 4; ++pb) {
                    const int plin = pa * 6 + pb, qlin = qa * 6 + qb;
                    if (plin >= qlin) continue;
                    const int pidx = (pa - 1) * 4 + (pb - 1);
                    const int qidx = (qa - 1) * 4 + (qb - 1);
                    const int hi = pair_hi(pa, pb, qa, qb);   // bounds of d2p - d2q
                    const int lo = pair_lo(pa, pb, qa, qb);
                    if (hi < 0) {
                        rank[qidx] += (exy[pa] & exx[pb]);    // p always beats q
                    } else if (lo > 0) {
                        rank[pidx] += (exy[qa] & exx[qb]);    // q always strictly beats p
                    } else {
                        // tie -> p (lower index): exactly one of the pair counts
                        int t = (d2[plin] <= d2[qlin]) ? 1 : 0;
                        rank[qidx] += t;
                        rank[pidx] += 1 - t;
                    }
                }
            }
        }
    }

    // ---- cubic conv (only 4 distinct args per axis) + masked accumulate ----
    float cvx[4], cvy[4];
    #pragma unroll
    for (int i = 0; i < 4; ++i) {
        cvx[i] = cubic_conv(sxv[i + 1]);   // fx - {-1,0,1,2}
        cvy[i] = cubic_conv(syv[i + 1]);
    }

    float res = 0.0f;
    #pragma unroll
    for (int s = 0; s < 16; ++s) {
        int sa = s >> 2, sb = s & 3;
        bool ok = (rank[s] < 16) && ((exy[sa + 1] & exx[sb + 1]) != 0);
        float term = wv[s] * (cvx[sb] * cvy[sa]);
        res += ok ? term : 0.0f;
    }
    out[q] = res;
}

extern "C" void kernel_launch(void* const* d_in, const int* in_sizes, int n_in,
                              void* d_out, int out_size, void* d_ws, size_t ws_size,
                              hipStream_t stream) {
    const float* x = (const float*)d_in[0];
    const float* w = (const float*)d_in[1];
    // d_in[2] (control_points) no longer needed: uniform grid computed in-kernel
    float* out = (float*)d_out;
    spline_fwd<<<dim3(NB / 64), dim3(64), 0, stream>>>(x, w, out);
}